// Round 2
// baseline (515.718 us; speedup 1.0000x reference)
//
#include <hip/hip_runtime.h>

#define N_NODES 100000
#define N_EDGES 1600000
#define IN_C 32
#define HID_C 64
#define OUT_C 32

// One thread per (edge, channel): lane-coalesced gather of feat[src], atomic
// scatter-add into agg[dst]. Optionally accumulates degree (from channel-0 lanes).
__global__ __launch_bounds__(256) void scatter32_kernel(
    const float* __restrict__ feat,   // [N_NODES, 32]
    const int* __restrict__ src,      // [N_EDGES]
    const int* __restrict__ dst,      // [N_EDGES]
    float* __restrict__ agg,          // [N_NODES, 32] (pre-zeroed)
    float* __restrict__ deg)          // [N_NODES] or nullptr
{
    long long idx = (long long)blockIdx.x * blockDim.x + threadIdx.x;
    if (idx >= (long long)N_EDGES * 32) return;
    int e = (int)(idx >> 5);
    int c = (int)(idx & 31);
    int s = src[e];
    int d = dst[e];
    atomicAdd(&agg[d * 32 + c], feat[s * 32 + c]);
    if (deg != nullptr && c == 0) atomicAdd(&deg[d], 1.0f);
}

// Per-node fused: mean1 = agg1/deg; h = relu(mean1@W1l^T + x@W1r^T + b1);
// t = h@W2l^T (to be scattered for layer 2); r = h@W2r^T + b2 (root term).
__global__ __launch_bounds__(256) void node_transform_kernel(
    const float* __restrict__ x,      // [N,32]
    const float* __restrict__ agg1,   // [N,32]
    const float* __restrict__ deg,    // [N]
    const float* __restrict__ W1l,    // [64,32]
    const float* __restrict__ W1r,    // [64,32]
    const float* __restrict__ b1,     // [64]
    const float* __restrict__ W2l,    // [32,64]
    const float* __restrict__ W2r,    // [32,64]
    const float* __restrict__ b2,     // [32]
    float* __restrict__ t,            // [N,32]
    float* __restrict__ r)            // [N,32]
{
    __shared__ float sW1l[HID_C * IN_C];
    __shared__ float sW1r[HID_C * IN_C];
    __shared__ float sW2l[OUT_C * HID_C];
    __shared__ float sW2r[OUT_C * HID_C];
    __shared__ float sb1[HID_C];
    __shared__ float sb2[OUT_C];

    for (int i = threadIdx.x; i < HID_C * IN_C; i += blockDim.x) {
        sW1l[i] = W1l[i];
        sW1r[i] = W1r[i];
    }
    for (int i = threadIdx.x; i < OUT_C * HID_C; i += blockDim.x) {
        sW2l[i] = W2l[i];
        sW2r[i] = W2r[i];
    }
    if (threadIdx.x < HID_C) sb1[threadIdx.x] = b1[threadIdx.x];
    if (threadIdx.x < OUT_C) sb2[threadIdx.x] = b2[threadIdx.x];
    __syncthreads();

    int n = blockIdx.x * blockDim.x + threadIdx.x;
    if (n >= N_NODES) return;

    float inv = 1.0f / fmaxf(deg[n], 1.0f);

    float xv[IN_C];
    float mv[IN_C];
    const float4* xp = (const float4*)&x[(long long)n * IN_C];
    const float4* ap = (const float4*)&agg1[(long long)n * IN_C];
#pragma unroll
    for (int c4 = 0; c4 < IN_C / 4; ++c4) {
        float4 xq = xp[c4];
        float4 aq = ap[c4];
        xv[c4 * 4 + 0] = xq.x; xv[c4 * 4 + 1] = xq.y;
        xv[c4 * 4 + 2] = xq.z; xv[c4 * 4 + 3] = xq.w;
        mv[c4 * 4 + 0] = aq.x * inv; mv[c4 * 4 + 1] = aq.y * inv;
        mv[c4 * 4 + 2] = aq.z * inv; mv[c4 * 4 + 3] = aq.w * inv;
    }

    float tacc[OUT_C];
    float racc[OUT_C];
#pragma unroll
    for (int k = 0; k < OUT_C; ++k) {
        tacc[k] = 0.0f;
        racc[k] = sb2[k];
    }

    for (int j = 0; j < HID_C; ++j) {
        float acc = sb1[j];
#pragma unroll
        for (int c = 0; c < IN_C; ++c) {
            acc += mv[c] * sW1l[j * IN_C + c] + xv[c] * sW1r[j * IN_C + c];
        }
        float hj = fmaxf(acc, 0.0f);
#pragma unroll
        for (int k = 0; k < OUT_C; ++k) {
            tacc[k] += hj * sW2l[k * HID_C + j];
            racc[k] += hj * sW2r[k * HID_C + j];
        }
    }

    float4* tp = (float4*)&t[(long long)n * OUT_C];
    float4* rp = (float4*)&r[(long long)n * OUT_C];
#pragma unroll
    for (int k4 = 0; k4 < OUT_C / 4; ++k4) {
        tp[k4] = make_float4(tacc[k4 * 4 + 0], tacc[k4 * 4 + 1],
                             tacc[k4 * 4 + 2], tacc[k4 * 4 + 3]);
        rp[k4] = make_float4(racc[k4 * 4 + 0], racc[k4 * 4 + 1],
                             racc[k4 * 4 + 2], racc[k4 * 4 + 3]);
    }
}

// out = agg2/max(deg,1) + r
__global__ __launch_bounds__(256) void finalize_kernel(
    const float* __restrict__ agg2,
    const float* __restrict__ deg,
    const float* __restrict__ r,
    float* __restrict__ out)
{
    int idx = blockIdx.x * blockDim.x + threadIdx.x;
    if (idx >= N_NODES * OUT_C) return;
    int n = idx >> 5;
    out[idx] = agg2[idx] / fmaxf(deg[n], 1.0f) + r[idx];
}

extern "C" void kernel_launch(void* const* d_in, const int* in_sizes, int n_in,
                              void* d_out, int out_size, void* d_ws, size_t ws_size,
                              hipStream_t stream) {
    const float* x   = (const float*)d_in[0];
    const float* W1l = (const float*)d_in[1];
    const float* W1r = (const float*)d_in[2];
    const float* b1  = (const float*)d_in[3];
    const float* W2l = (const float*)d_in[4];
    const float* W2r = (const float*)d_in[5];
    const float* b2  = (const float*)d_in[6];
    const int*   ei  = (const int*)d_in[7];   // [2, N_EDGES]
    const int* src = ei;
    const int* dst = ei + N_EDGES;

    float* ws   = (float*)d_ws;
    float* deg  = ws;                              // N_NODES
    float* agg1 = ws + N_NODES;                    // N_NODES*32
    float* agg2 = agg1 + (size_t)N_NODES * 32;     // N_NODES*32
    float* t    = agg2 + (size_t)N_NODES * 32;     // N_NODES*32
    float* r    = t + (size_t)N_NODES * 32;        // N_NODES*32

    // zero deg + agg1 + agg2 in one memset (they are contiguous)
    hipMemsetAsync(ws, 0, (size_t)(N_NODES + 2 * N_NODES * 32) * sizeof(float), stream);

    dim3 blk(256);
    int egrid = (int)(((long long)N_EDGES * 32 + 255) / 256);
    int ngrid = (N_NODES + 255) / 256;
    int fgrid = (N_NODES * OUT_C + 255) / 256;

    scatter32_kernel<<<egrid, blk, 0, stream>>>(x, src, dst, agg1, deg);
    node_transform_kernel<<<ngrid, blk, 0, stream>>>(x, agg1, deg, W1l, W1r, b1,
                                                     W2l, W2r, b2, t, r);
    scatter32_kernel<<<egrid, blk, 0, stream>>>(t, src, dst, agg2, nullptr);
    finalize_kernel<<<fgrid, blk, 0, stream>>>(agg2, deg, r, (float*)d_out);
}

// Round 3
// 466.020 us; speedup vs baseline: 1.1066x; 1.1066x over previous
//
#include <hip/hip_runtime.h>

#define N_NODES 100000
#define N_EDGES 1600000
#define IN_C 32
#define HID_C 64
#define OUT_C 32

#define SCAN_CHUNK 4096
#define NCHUNKS ((N_NODES + SCAN_CHUNK - 1) / SCAN_CHUNK)   // 25

// ---- CSR build ----------------------------------------------------------

__global__ __launch_bounds__(256) void hist_kernel(
    const int* __restrict__ dst, int* __restrict__ counts) {
    int e = blockIdx.x * blockDim.x + threadIdx.x;
    if (e < N_EDGES) atomicAdd(&counts[dst[e]], 1);
}

__global__ __launch_bounds__(256) void chunk_sum_kernel(
    const int* __restrict__ counts, int* __restrict__ chunkSums) {
    __shared__ int sd[256];
    int base = blockIdx.x * SCAN_CHUNK + threadIdx.x * 16;
    int s = 0;
#pragma unroll
    for (int i = 0; i < 16; ++i) {
        int n = base + i;
        if (n < N_NODES) s += counts[n];
    }
    sd[threadIdx.x] = s;
    __syncthreads();
    for (int o = 128; o > 0; o >>= 1) {
        if (threadIdx.x < o) sd[threadIdx.x] += sd[threadIdx.x + o];
        __syncthreads();
    }
    if (threadIdx.x == 0) chunkSums[blockIdx.x] = sd[0];
}

__global__ void chunk_scan_kernel(const int* __restrict__ chunkSums,
                                  int* __restrict__ chunkOff) {
    int acc = 0;
    for (int i = 0; i < NCHUNKS; ++i) { chunkOff[i] = acc; acc += chunkSums[i]; }
}

// exclusive scan of counts -> rowptr (and a second copy 'pos' used as running
// insert cursors by the reorder kernel)
__global__ __launch_bounds__(256) void scan_write_kernel(
    const int* __restrict__ counts, const int* __restrict__ chunkOff,
    int* __restrict__ rowptr, int* __restrict__ pos) {
    __shared__ int sincl[256];
    int tid = threadIdx.x;
    int base = blockIdx.x * SCAN_CHUNK + tid * 16;
    int local[16];
    int s = 0;
#pragma unroll
    for (int i = 0; i < 16; ++i) {
        int n = base + i;
        int c = (n < N_NODES) ? counts[n] : 0;
        local[i] = s;
        s += c;
    }
    sincl[tid] = s;
    __syncthreads();
    for (int o = 1; o < 256; o <<= 1) {
        int v = (tid >= o) ? sincl[tid - o] : 0;
        __syncthreads();
        sincl[tid] += v;
        __syncthreads();
    }
    int texcl = sincl[tid] - s + chunkOff[blockIdx.x];
#pragma unroll
    for (int i = 0; i < 16; ++i) {
        int n = base + i;
        if (n < N_NODES) {
            int v = texcl + local[i];
            rowptr[n] = v;
            pos[n] = v;
        }
    }
}

__global__ __launch_bounds__(256) void reorder_kernel(
    const int* __restrict__ src, const int* __restrict__ dst,
    int* __restrict__ pos, int* __restrict__ perm) {
    int e = blockIdx.x * blockDim.x + threadIdx.x;
    if (e < N_EDGES) {
        int p = atomicAdd(&pos[dst[e]], 1);
        perm[p] = src[e];
    }
}

// ---- aggregation by gather ---------------------------------------------
// One 64-lane wave per node: two 32-lane halves each read a full 128B feature
// row (coalesced), walking the node's CSR segment 2 edges/iteration.

__global__ __launch_bounds__(256) void gather_mean_kernel(
    const float* __restrict__ feat,     // [N,32]
    const int* __restrict__ rowptr, const int* __restrict__ counts,
    const int* __restrict__ perm,
    float* __restrict__ meanout)        // [N,32]
{
    int lane = threadIdx.x & 63;
    int wid = threadIdx.x >> 6;
    int n = blockIdx.x * 4 + wid;
    if (n >= N_NODES) return;
    int c = lane & 31;
    int half = lane >> 5;
    int start = rowptr[n];
    int cnt = counts[n];
    float s = 0.0f;
    for (int i = start + half; i < start + cnt; i += 2)
        s += feat[(long long)perm[i] * 32 + c];
    s += __shfl_xor(s, 32, 64);
    if (half == 0)
        meanout[(long long)n * 32 + c] = s / fmaxf((float)cnt, 1.0f);
}

// layer-2 aggregation fused with finalize: out = mean(t[neighbors]) + r
__global__ __launch_bounds__(256) void gather_final_kernel(
    const float* __restrict__ t,        // [N,32]
    const int* __restrict__ rowptr, const int* __restrict__ counts,
    const int* __restrict__ perm,
    const float* __restrict__ r,        // [N,32]
    float* __restrict__ out)            // [N,32]
{
    int lane = threadIdx.x & 63;
    int wid = threadIdx.x >> 6;
    int n = blockIdx.x * 4 + wid;
    if (n >= N_NODES) return;
    int c = lane & 31;
    int half = lane >> 5;
    int start = rowptr[n];
    int cnt = counts[n];
    float s = 0.0f;
    for (int i = start + half; i < start + cnt; i += 2)
        s += t[(long long)perm[i] * 32 + c];
    s += __shfl_xor(s, 32, 64);
    if (half == 0)
        out[(long long)n * 32 + c] = s / fmaxf((float)cnt, 1.0f) + r[(long long)n * 32 + c];
}

// ---- per-node dense transform ------------------------------------------
// h = relu(mean1@W1l^T + x@W1r^T + b1); t = h@W2l^T; r = h@W2r^T + b2

__global__ __launch_bounds__(256) void node_transform_kernel(
    const float* __restrict__ x, const float* __restrict__ mean1,
    const float* __restrict__ W1l, const float* __restrict__ W1r,
    const float* __restrict__ b1, const float* __restrict__ W2l,
    const float* __restrict__ W2r, const float* __restrict__ b2,
    float* __restrict__ t, float* __restrict__ r)
{
    __shared__ float sW1l[HID_C * IN_C];
    __shared__ float sW1r[HID_C * IN_C];
    __shared__ float sW2l[OUT_C * HID_C];
    __shared__ float sW2r[OUT_C * HID_C];
    __shared__ float sb1[HID_C];
    __shared__ float sb2[OUT_C];

    for (int i = threadIdx.x; i < HID_C * IN_C; i += blockDim.x) {
        sW1l[i] = W1l[i];
        sW1r[i] = W1r[i];
    }
    for (int i = threadIdx.x; i < OUT_C * HID_C; i += blockDim.x) {
        sW2l[i] = W2l[i];
        sW2r[i] = W2r[i];
    }
    if (threadIdx.x < HID_C) sb1[threadIdx.x] = b1[threadIdx.x];
    if (threadIdx.x < OUT_C) sb2[threadIdx.x] = b2[threadIdx.x];
    __syncthreads();

    int n = blockIdx.x * blockDim.x + threadIdx.x;
    if (n >= N_NODES) return;

    float xv[IN_C];
    float mv[IN_C];
    const float4* xp = (const float4*)&x[(long long)n * IN_C];
    const float4* ap = (const float4*)&mean1[(long long)n * IN_C];
#pragma unroll
    for (int c4 = 0; c4 < IN_C / 4; ++c4) {
        float4 xq = xp[c4];
        float4 aq = ap[c4];
        xv[c4 * 4 + 0] = xq.x; xv[c4 * 4 + 1] = xq.y;
        xv[c4 * 4 + 2] = xq.z; xv[c4 * 4 + 3] = xq.w;
        mv[c4 * 4 + 0] = aq.x; mv[c4 * 4 + 1] = aq.y;
        mv[c4 * 4 + 2] = aq.z; mv[c4 * 4 + 3] = aq.w;
    }

    float tacc[OUT_C];
    float racc[OUT_C];
#pragma unroll
    for (int k = 0; k < OUT_C; ++k) {
        tacc[k] = 0.0f;
        racc[k] = sb2[k];
    }

    for (int j = 0; j < HID_C; ++j) {
        float acc = sb1[j];
#pragma unroll
        for (int c = 0; c < IN_C; ++c) {
            acc += mv[c] * sW1l[j * IN_C + c] + xv[c] * sW1r[j * IN_C + c];
        }
        float hj = fmaxf(acc, 0.0f);
#pragma unroll
        for (int k = 0; k < OUT_C; ++k) {
            tacc[k] += hj * sW2l[k * HID_C + j];
            racc[k] += hj * sW2r[k * HID_C + j];
        }
    }

    float4* tp = (float4*)&t[(long long)n * OUT_C];
    float4* rp = (float4*)&r[(long long)n * OUT_C];
#pragma unroll
    for (int k4 = 0; k4 < OUT_C / 4; ++k4) {
        tp[k4] = make_float4(tacc[k4 * 4 + 0], tacc[k4 * 4 + 1],
                             tacc[k4 * 4 + 2], tacc[k4 * 4 + 3]);
        rp[k4] = make_float4(racc[k4 * 4 + 0], racc[k4 * 4 + 1],
                             racc[k4 * 4 + 2], racc[k4 * 4 + 3]);
    }
}

// ---- launch -------------------------------------------------------------

extern "C" void kernel_launch(void* const* d_in, const int* in_sizes, int n_in,
                              void* d_out, int out_size, void* d_ws, size_t ws_size,
                              hipStream_t stream) {
    const float* x   = (const float*)d_in[0];
    const float* W1l = (const float*)d_in[1];
    const float* W1r = (const float*)d_in[2];
    const float* b1  = (const float*)d_in[3];
    const float* W2l = (const float*)d_in[4];
    const float* W2r = (const float*)d_in[5];
    const float* b2  = (const float*)d_in[6];
    const int*   ei  = (const int*)d_in[7];   // [2, N_EDGES]
    const int* src = ei;
    const int* dst = ei + N_EDGES;

    char* ws = (char*)d_ws;
    int*   counts    = (int*)ws;                                   ws += (size_t)N_NODES * 4;
    int*   rowptr    = (int*)ws;                                   ws += (size_t)N_NODES * 4;
    int*   pos       = (int*)ws;                                   ws += (size_t)N_NODES * 4;
    int*   chunkSums = (int*)ws;                                   ws += 32 * 4;
    int*   chunkOff  = (int*)ws;                                   ws += 32 * 4;
    int*   perm      = (int*)ws;                                   ws += (size_t)N_EDGES * 4;
    float* mean1     = (float*)ws;                                 ws += (size_t)N_NODES * IN_C * 4;
    float* t         = (float*)ws;                                 ws += (size_t)N_NODES * OUT_C * 4;
    float* r         = (float*)ws;                                 ws += (size_t)N_NODES * OUT_C * 4;

    hipMemsetAsync(counts, 0, (size_t)N_NODES * 4, stream);

    dim3 blk(256);
    int egrid = (N_EDGES + 255) / 256;
    int ngrid = (N_NODES + 255) / 256;
    int ggrid = (N_NODES + 3) / 4;     // 4 waves/block, 1 wave per node

    hist_kernel<<<egrid, blk, 0, stream>>>(dst, counts);
    chunk_sum_kernel<<<NCHUNKS, blk, 0, stream>>>(counts, chunkSums);
    chunk_scan_kernel<<<1, 1, 0, stream>>>(chunkSums, chunkOff);
    scan_write_kernel<<<NCHUNKS, blk, 0, stream>>>(counts, chunkOff, rowptr, pos);
    reorder_kernel<<<egrid, blk, 0, stream>>>(src, dst, pos, perm);

    gather_mean_kernel<<<ggrid, blk, 0, stream>>>(x, rowptr, counts, perm, mean1);
    node_transform_kernel<<<ngrid, blk, 0, stream>>>(x, mean1, W1l, W1r, b1,
                                                     W2l, W2r, b2, t, r);
    gather_final_kernel<<<ggrid, blk, 0, stream>>>(t, rowptr, counts, perm, r,
                                                   (float*)d_out);
}

// Round 4
// 298.580 us; speedup vs baseline: 1.7272x; 1.5608x over previous
//
#include <hip/hip_runtime.h>

#define N_NODES 100000
#define N_EDGES 1600000
#define IN_C 32
#define HID_C 64
#define OUT_C 32

#define SCAN_CHUNK 4096
#define NCHUNKS ((N_NODES + SCAN_CHUNK - 1) / SCAN_CHUNK)   // 25

#define EPB 1024                                 // edges per hist/place block
#define NBLK ((N_EDGES + EPB - 1) / EPB)         // 1563
#define BSH 9                                    // 512 nodes per bucket
#define BKN (1 << BSH)
#define NB ((N_NODES + BKN - 1) / BKN)           // 196

// ---- pass A: per-block bucket histogram + global per-node counts --------
__global__ __launch_bounds__(256) void bucket_hist_kernel(
    const int* __restrict__ dst, int* __restrict__ counts, int* __restrict__ gh) {
    __shared__ int lh[NB];
    for (int i = threadIdx.x; i < NB; i += 256) lh[i] = 0;
    __syncthreads();
    int base = blockIdx.x * EPB;
#pragma unroll
    for (int j = 0; j < EPB / 256; ++j) {
        int e = base + j * 256 + threadIdx.x;
        if (e < N_EDGES) {
            int d = dst[e];
            atomicAdd(&lh[d >> BSH], 1);
            atomicAdd(&counts[d], 1);
        }
    }
    __syncthreads();
    for (int i = threadIdx.x; i < NB; i += 256)
        gh[i * NBLK + blockIdx.x] = lh[i];
}

// ---- node-count scan -> rowptr ------------------------------------------
__global__ __launch_bounds__(256) void chunk_sum_kernel(
    const int* __restrict__ counts, int* __restrict__ chunkSums) {
    __shared__ int sd[256];
    int base = blockIdx.x * SCAN_CHUNK + threadIdx.x * 16;
    int s = 0;
#pragma unroll
    for (int i = 0; i < 16; ++i) {
        int n = base + i;
        if (n < N_NODES) s += counts[n];
    }
    sd[threadIdx.x] = s;
    __syncthreads();
    for (int o = 128; o > 0; o >>= 1) {
        if (threadIdx.x < o) sd[threadIdx.x] += sd[threadIdx.x + o];
        __syncthreads();
    }
    if (threadIdx.x == 0) chunkSums[blockIdx.x] = sd[0];
}

__global__ void chunk_scan_kernel(const int* __restrict__ chunkSums,
                                  int* __restrict__ chunkOff) {
    int acc = 0;
    for (int i = 0; i < NCHUNKS; ++i) { chunkOff[i] = acc; acc += chunkSums[i]; }
}

__global__ __launch_bounds__(256) void scan_write_kernel(
    const int* __restrict__ counts, const int* __restrict__ chunkOff,
    int* __restrict__ rowptr) {
    __shared__ int sincl[256];
    int tid = threadIdx.x;
    int base = blockIdx.x * SCAN_CHUNK + tid * 16;
    int local[16];
    int s = 0;
#pragma unroll
    for (int i = 0; i < 16; ++i) {
        int n = base + i;
        int c = (n < N_NODES) ? counts[n] : 0;
        local[i] = s;
        s += c;
    }
    sincl[tid] = s;
    __syncthreads();
    for (int o = 1; o < 256; o <<= 1) {
        int v = (tid >= o) ? sincl[tid - o] : 0;
        __syncthreads();
        sincl[tid] += v;
        __syncthreads();
    }
    int texcl = sincl[tid] - s + chunkOff[blockIdx.x];
#pragma unroll
    for (int i = 0; i < 16; ++i) {
        int n = base + i;
        if (n < N_NODES) rowptr[n] = texcl + local[i];
    }
}

// ---- pass B: per-bucket exclusive scan of gh across blocks --------------
// gh[b][k] becomes the global slot offset for block k's edges of bucket b.
__global__ __launch_bounds__(256) void bucket_scan_kernel(
    const int* __restrict__ rowptr, int* __restrict__ gh) {
    int b = blockIdx.x;
    int t = threadIdx.x;
    __shared__ int ssum[256];
    int v[7];
    int base = t * 7;
    int s = 0;
#pragma unroll
    for (int j = 0; j < 7; ++j) {
        int idx = base + j;
        int val = (idx < NBLK) ? gh[b * NBLK + idx] : 0;
        v[j] = s;
        s += val;
    }
    ssum[t] = s;
    __syncthreads();
    for (int o = 1; o < 256; o <<= 1) {
        int val = (t >= o) ? ssum[t - o] : 0;
        __syncthreads();
        ssum[t] += val;
        __syncthreads();
    }
    int texcl = ssum[t] - s;
    int boff = rowptr[b << BSH];   // bucket base in edge space (free from node scan)
#pragma unroll
    for (int j = 0; j < 7; ++j) {
        int idx = base + j;
        if (idx < NBLK) gh[b * NBLK + idx] = boff + texcl + v[j];
    }
}

// ---- pass C: place (src,dst) pairs into bucket-sorted tmp ---------------
// Writes for a given (block,bucket) are consecutive -> line-friendly.
__global__ __launch_bounds__(256) void bucket_place_kernel(
    const int* __restrict__ src, const int* __restrict__ dst,
    const int* __restrict__ gh, uint2* __restrict__ tmp) {
    __shared__ int cur[NB];
    for (int i = threadIdx.x; i < NB; i += 256)
        cur[i] = gh[i * NBLK + blockIdx.x];
    __syncthreads();
    int base = blockIdx.x * EPB;
#pragma unroll
    for (int j = 0; j < EPB / 256; ++j) {
        int e = base + j * 256 + threadIdx.x;
        if (e < N_EDGES) {
            int d = dst[e];
            int slot = atomicAdd(&cur[d >> BSH], 1);
            tmp[slot] = make_uint2((unsigned)src[e], (unsigned)d);
        }
    }
}

// ---- pass D: within-bucket per-node placement via LDS cursors -----------
__global__ __launch_bounds__(512) void node_place_kernel(
    const uint2* __restrict__ tmp, const int* __restrict__ rowptr,
    int* __restrict__ perm) {
    __shared__ int pos[BKN];
    int b = blockIdx.x;
    int nbase = b << BSH;
    for (int j = threadIdx.x; j < BKN; j += 512) {
        int n = nbase + j;
        pos[j] = (n < N_NODES) ? rowptr[n] : 0;
    }
    __syncthreads();
    int start = rowptr[nbase];
    int end = (b == NB - 1) ? N_EDGES : rowptr[nbase + BKN];
    for (int i = start + threadIdx.x; i < end; i += 512) {
        uint2 p = tmp[i];
        int slot = atomicAdd(&pos[p.y & (BKN - 1)], 1);
        perm[slot] = (int)p.x;
    }
}

// ---- gathers: one wave per node, 8 edges x float4 in flight -------------
__global__ __launch_bounds__(256) void gather_mean_kernel(
    const float* __restrict__ feat, const int* __restrict__ rowptr,
    const int* __restrict__ counts, const int* __restrict__ perm,
    float* __restrict__ meanout) {
    int lane = threadIdx.x & 63;
    int wid = threadIdx.x >> 6;
    int n = blockIdx.x * 4 + wid;
    if (n >= N_NODES) return;
    int g = lane >> 3;      // edge slot within chunk of 8
    int q = lane & 7;       // channel quad
    int start = rowptr[n];
    int cnt = counts[n];
    int end = start + cnt;
    float4 acc = make_float4(0.f, 0.f, 0.f, 0.f);
    for (int i = start + g; i < end; i += 8) {
        int idx = perm[i];
        float4 v = ((const float4*)&feat[(long long)idx * 32])[q];
        acc.x += v.x; acc.y += v.y; acc.z += v.z; acc.w += v.w;
    }
#pragma unroll
    for (int off = 8; off < 64; off <<= 1) {
        acc.x += __shfl_xor(acc.x, off, 64);
        acc.y += __shfl_xor(acc.y, off, 64);
        acc.z += __shfl_xor(acc.z, off, 64);
        acc.w += __shfl_xor(acc.w, off, 64);
    }
    if (g == 0) {
        float inv = 1.0f / fmaxf((float)cnt, 1.0f);
        ((float4*)&meanout[(long long)n * 32])[q] =
            make_float4(acc.x * inv, acc.y * inv, acc.z * inv, acc.w * inv);
    }
}

__global__ __launch_bounds__(256) void gather_final_kernel(
    const float* __restrict__ t, const int* __restrict__ rowptr,
    const int* __restrict__ counts, const int* __restrict__ perm,
    const float* __restrict__ r, float* __restrict__ out) {
    int lane = threadIdx.x & 63;
    int wid = threadIdx.x >> 6;
    int n = blockIdx.x * 4 + wid;
    if (n >= N_NODES) return;
    int g = lane >> 3;
    int q = lane & 7;
    int start = rowptr[n];
    int cnt = counts[n];
    int end = start + cnt;
    float4 acc = make_float4(0.f, 0.f, 0.f, 0.f);
    for (int i = start + g; i < end; i += 8) {
        int idx = perm[i];
        float4 v = ((const float4*)&t[(long long)idx * 32])[q];
        acc.x += v.x; acc.y += v.y; acc.z += v.z; acc.w += v.w;
    }
#pragma unroll
    for (int off = 8; off < 64; off <<= 1) {
        acc.x += __shfl_xor(acc.x, off, 64);
        acc.y += __shfl_xor(acc.y, off, 64);
        acc.z += __shfl_xor(acc.z, off, 64);
        acc.w += __shfl_xor(acc.w, off, 64);
    }
    if (g == 0) {
        float inv = 1.0f / fmaxf((float)cnt, 1.0f);
        float4 rv = ((const float4*)&r[(long long)n * 32])[q];
        ((float4*)&out[(long long)n * 32])[q] =
            make_float4(acc.x * inv + rv.x, acc.y * inv + rv.y,
                        acc.z * inv + rv.z, acc.w * inv + rv.w);
    }
}

// ---- per-node dense transform (unchanged) -------------------------------
__global__ __launch_bounds__(256) void node_transform_kernel(
    const float* __restrict__ x, const float* __restrict__ mean1,
    const float* __restrict__ W1l, const float* __restrict__ W1r,
    const float* __restrict__ b1, const float* __restrict__ W2l,
    const float* __restrict__ W2r, const float* __restrict__ b2,
    float* __restrict__ t, float* __restrict__ r)
{
    __shared__ float sW1l[HID_C * IN_C];
    __shared__ float sW1r[HID_C * IN_C];
    __shared__ float sW2l[OUT_C * HID_C];
    __shared__ float sW2r[OUT_C * HID_C];
    __shared__ float sb1[HID_C];
    __shared__ float sb2[OUT_C];

    for (int i = threadIdx.x; i < HID_C * IN_C; i += blockDim.x) {
        sW1l[i] = W1l[i];
        sW1r[i] = W1r[i];
    }
    for (int i = threadIdx.x; i < OUT_C * HID_C; i += blockDim.x) {
        sW2l[i] = W2l[i];
        sW2r[i] = W2r[i];
    }
    if (threadIdx.x < HID_C) sb1[threadIdx.x] = b1[threadIdx.x];
    if (threadIdx.x < OUT_C) sb2[threadIdx.x] = b2[threadIdx.x];
    __syncthreads();

    int n = blockIdx.x * blockDim.x + threadIdx.x;
    if (n >= N_NODES) return;

    float xv[IN_C];
    float mv[IN_C];
    const float4* xp = (const float4*)&x[(long long)n * IN_C];
    const float4* ap = (const float4*)&mean1[(long long)n * IN_C];
#pragma unroll
    for (int c4 = 0; c4 < IN_C / 4; ++c4) {
        float4 xq = xp[c4];
        float4 aq = ap[c4];
        xv[c4 * 4 + 0] = xq.x; xv[c4 * 4 + 1] = xq.y;
        xv[c4 * 4 + 2] = xq.z; xv[c4 * 4 + 3] = xq.w;
        mv[c4 * 4 + 0] = aq.x; mv[c4 * 4 + 1] = aq.y;
        mv[c4 * 4 + 2] = aq.z; mv[c4 * 4 + 3] = aq.w;
    }

    float tacc[OUT_C];
    float racc[OUT_C];
#pragma unroll
    for (int k = 0; k < OUT_C; ++k) {
        tacc[k] = 0.0f;
        racc[k] = sb2[k];
    }

    for (int j = 0; j < HID_C; ++j) {
        float acc = sb1[j];
#pragma unroll
        for (int c = 0; c < IN_C; ++c) {
            acc += mv[c] * sW1l[j * IN_C + c] + xv[c] * sW1r[j * IN_C + c];
        }
        float hj = fmaxf(acc, 0.0f);
#pragma unroll
        for (int k = 0; k < OUT_C; ++k) {
            tacc[k] += hj * sW2l[k * HID_C + j];
            racc[k] += hj * sW2r[k * HID_C + j];
        }
    }

    float4* tp = (float4*)&t[(long long)n * OUT_C];
    float4* rp = (float4*)&r[(long long)n * OUT_C];
#pragma unroll
    for (int k4 = 0; k4 < OUT_C / 4; ++k4) {
        tp[k4] = make_float4(tacc[k4 * 4 + 0], tacc[k4 * 4 + 1],
                             tacc[k4 * 4 + 2], tacc[k4 * 4 + 3]);
        rp[k4] = make_float4(racc[k4 * 4 + 0], racc[k4 * 4 + 1],
                             racc[k4 * 4 + 2], racc[k4 * 4 + 3]);
    }
}

// ---- launch -------------------------------------------------------------

extern "C" void kernel_launch(void* const* d_in, const int* in_sizes, int n_in,
                              void* d_out, int out_size, void* d_ws, size_t ws_size,
                              hipStream_t stream) {
    const float* x   = (const float*)d_in[0];
    const float* W1l = (const float*)d_in[1];
    const float* W1r = (const float*)d_in[2];
    const float* b1  = (const float*)d_in[3];
    const float* W2l = (const float*)d_in[4];
    const float* W2r = (const float*)d_in[5];
    const float* b2  = (const float*)d_in[6];
    const int*   ei  = (const int*)d_in[7];   // [2, N_EDGES]
    const int* src = ei;
    const int* dst = ei + N_EDGES;

    char* ws = (char*)d_ws;
    int*   counts    = (int*)ws;                ws += (size_t)N_NODES * 4;
    int*   rowptr    = (int*)ws;                ws += (size_t)N_NODES * 4;
    int*   chunkSums = (int*)ws;                ws += 64 * 4;
    int*   chunkOff  = (int*)ws;                ws += 64 * 4;
    int*   gh        = (int*)ws;                ws += (size_t)NB * NBLK * 4;
    int*   perm      = (int*)ws;                ws += (size_t)N_EDGES * 4;
    uint2* tmp       = (uint2*)ws;              ws += (size_t)N_EDGES * 8;
    // mean1 aliases tmp: tmp is dead after node_place_kernel, mean1 written after.
    float* mean1     = (float*)tmp;
    float* t         = (float*)ws;              ws += (size_t)N_NODES * OUT_C * 4;
    float* r         = (float*)ws;              ws += (size_t)N_NODES * OUT_C * 4;

    hipMemsetAsync(counts, 0, (size_t)N_NODES * 4, stream);

    dim3 blk(256);
    int ngrid = (N_NODES + 255) / 256;
    int ggrid = (N_NODES + 3) / 4;

    bucket_hist_kernel<<<NBLK, blk, 0, stream>>>(dst, counts, gh);
    chunk_sum_kernel<<<NCHUNKS, blk, 0, stream>>>(counts, chunkSums);
    chunk_scan_kernel<<<1, 1, 0, stream>>>(chunkSums, chunkOff);
    scan_write_kernel<<<NCHUNKS, blk, 0, stream>>>(counts, chunkOff, rowptr);
    bucket_scan_kernel<<<NB, blk, 0, stream>>>(rowptr, gh);
    bucket_place_kernel<<<NBLK, blk, 0, stream>>>(src, dst, gh, tmp);
    node_place_kernel<<<NB, dim3(512), 0, stream>>>(tmp, rowptr, perm);

    gather_mean_kernel<<<ggrid, blk, 0, stream>>>(x, rowptr, counts, perm, mean1);
    node_transform_kernel<<<ngrid, blk, 0, stream>>>(x, mean1, W1l, W1r, b1,
                                                     W2l, W2r, b2, t, r);
    gather_final_kernel<<<ggrid, blk, 0, stream>>>(t, rowptr, counts, perm, r,
                                                   (float*)d_out);
}

// Round 5
// 285.966 us; speedup vs baseline: 1.8034x; 1.0441x over previous
//
#include <hip/hip_runtime.h>

#define N_NODES 100000
#define N_EDGES 1600000
#define IN_C 32
#define HID_C 64
#define OUT_C 32

#define SCAN_CHUNK 4096
#define NCHUNKS ((N_NODES + SCAN_CHUNK - 1) / SCAN_CHUNK)   // 25

#define EPB 1024                                 // edges per hist/place block
#define NBLK ((N_EDGES + EPB - 1) / EPB)         // 1563
#define BSH 9                                    // 512 nodes per bucket
#define BKN (1 << BSH)
#define NB ((N_NODES + BKN - 1) / BKN)           // 196

// ---- pass A: per-block bucket histogram + global per-node counts --------
__global__ __launch_bounds__(256) void bucket_hist_kernel(
    const int* __restrict__ dst, int* __restrict__ counts, int* __restrict__ gh) {
    __shared__ int lh[NB];
    for (int i = threadIdx.x; i < NB; i += 256) lh[i] = 0;
    __syncthreads();
    int base = blockIdx.x * EPB;
#pragma unroll
    for (int j = 0; j < EPB / 256; ++j) {
        int e = base + j * 256 + threadIdx.x;
        if (e < N_EDGES) {
            int d = dst[e];
            atomicAdd(&lh[d >> BSH], 1);
            atomicAdd(&counts[d], 1);
        }
    }
    __syncthreads();
    for (int i = threadIdx.x; i < NB; i += 256)
        gh[i * NBLK + blockIdx.x] = lh[i];
}

// ---- node-count scan -> rowptr ------------------------------------------
__global__ __launch_bounds__(256) void chunk_sum_kernel(
    const int* __restrict__ counts, int* __restrict__ chunkSums) {
    __shared__ int sd[256];
    int base = blockIdx.x * SCAN_CHUNK + threadIdx.x * 16;
    int s = 0;
#pragma unroll
    for (int i = 0; i < 16; ++i) {
        int n = base + i;
        if (n < N_NODES) s += counts[n];
    }
    sd[threadIdx.x] = s;
    __syncthreads();
    for (int o = 128; o > 0; o >>= 1) {
        if (threadIdx.x < o) sd[threadIdx.x] += sd[threadIdx.x + o];
        __syncthreads();
    }
    if (threadIdx.x == 0) chunkSums[blockIdx.x] = sd[0];
}

__global__ void chunk_scan_kernel(const int* __restrict__ chunkSums,
                                  int* __restrict__ chunkOff) {
    int acc = 0;
    for (int i = 0; i < NCHUNKS; ++i) { chunkOff[i] = acc; acc += chunkSums[i]; }
}

__global__ __launch_bounds__(256) void scan_write_kernel(
    const int* __restrict__ counts, const int* __restrict__ chunkOff,
    int* __restrict__ rowptr) {
    __shared__ int sincl[256];
    int tid = threadIdx.x;
    int base = blockIdx.x * SCAN_CHUNK + tid * 16;
    int local[16];
    int s = 0;
#pragma unroll
    for (int i = 0; i < 16; ++i) {
        int n = base + i;
        int c = (n < N_NODES) ? counts[n] : 0;
        local[i] = s;
        s += c;
    }
    sincl[tid] = s;
    __syncthreads();
    for (int o = 1; o < 256; o <<= 1) {
        int v = (tid >= o) ? sincl[tid - o] : 0;
        __syncthreads();
        sincl[tid] += v;
        __syncthreads();
    }
    int texcl = sincl[tid] - s + chunkOff[blockIdx.x];
#pragma unroll
    for (int i = 0; i < 16; ++i) {
        int n = base + i;
        if (n < N_NODES) rowptr[n] = texcl + local[i];
    }
}

// ---- pass B: per-bucket exclusive scan of gh across blocks --------------
__global__ __launch_bounds__(256) void bucket_scan_kernel(
    const int* __restrict__ rowptr, int* __restrict__ gh) {
    int b = blockIdx.x;
    int t = threadIdx.x;
    __shared__ int ssum[256];
    int v[7];
    int base = t * 7;
    int s = 0;
#pragma unroll
    for (int j = 0; j < 7; ++j) {
        int idx = base + j;
        int val = (idx < NBLK) ? gh[b * NBLK + idx] : 0;
        v[j] = s;
        s += val;
    }
    ssum[t] = s;
    __syncthreads();
    for (int o = 1; o < 256; o <<= 1) {
        int val = (t >= o) ? ssum[t - o] : 0;
        __syncthreads();
        ssum[t] += val;
        __syncthreads();
    }
    int texcl = ssum[t] - s;
    int boff = rowptr[b << BSH];
#pragma unroll
    for (int j = 0; j < 7; ++j) {
        int idx = base + j;
        if (idx < NBLK) gh[b * NBLK + idx] = boff + texcl + v[j];
    }
}

// ---- pass C: place (src,dst) pairs into bucket-sorted tmp ---------------
__global__ __launch_bounds__(256) void bucket_place_kernel(
    const int* __restrict__ src, const int* __restrict__ dst,
    const int* __restrict__ gh, uint2* __restrict__ tmp) {
    __shared__ int cur[NB];
    for (int i = threadIdx.x; i < NB; i += 256)
        cur[i] = gh[i * NBLK + blockIdx.x];
    __syncthreads();
    int base = blockIdx.x * EPB;
#pragma unroll
    for (int j = 0; j < EPB / 256; ++j) {
        int e = base + j * 256 + threadIdx.x;
        if (e < N_EDGES) {
            int d = dst[e];
            int slot = atomicAdd(&cur[d >> BSH], 1);
            tmp[slot] = make_uint2((unsigned)src[e], (unsigned)d);
        }
    }
}

// ---- pass D: within-bucket per-node placement via LDS cursors -----------
__global__ __launch_bounds__(512) void node_place_kernel(
    const uint2* __restrict__ tmp, const int* __restrict__ rowptr,
    int* __restrict__ perm) {
    __shared__ int pos[BKN];
    int b = blockIdx.x;
    int nbase = b << BSH;
    for (int j = threadIdx.x; j < BKN; j += 512) {
        int n = nbase + j;
        pos[j] = (n < N_NODES) ? rowptr[n] : 0;
    }
    __syncthreads();
    int start = rowptr[nbase];
    int end = (b == NB - 1) ? N_EDGES : rowptr[nbase + BKN];
    for (int i = start + threadIdx.x; i < end; i += 512) {
        uint2 p = tmp[i];
        int slot = atomicAdd(&pos[p.y & (BKN - 1)], 1);
        perm[slot] = (int)p.x;
    }
}

// ---- gathers: one wave per node, 8 edges x float4 in flight -------------
__global__ __launch_bounds__(256) void gather_mean_kernel(
    const float* __restrict__ feat, const int* __restrict__ rowptr,
    const int* __restrict__ counts, const int* __restrict__ perm,
    float* __restrict__ meanout) {
    int lane = threadIdx.x & 63;
    int wid = threadIdx.x >> 6;
    int n = blockIdx.x * 4 + wid;
    if (n >= N_NODES) return;
    int g = lane >> 3;
    int q = lane & 7;
    int start = rowptr[n];
    int cnt = counts[n];
    int end = start + cnt;
    float4 acc = make_float4(0.f, 0.f, 0.f, 0.f);
    for (int i = start + g; i < end; i += 8) {
        int idx = perm[i];
        float4 v = ((const float4*)&feat[(long long)idx * 32])[q];
        acc.x += v.x; acc.y += v.y; acc.z += v.z; acc.w += v.w;
    }
#pragma unroll
    for (int off = 8; off < 64; off <<= 1) {
        acc.x += __shfl_xor(acc.x, off, 64);
        acc.y += __shfl_xor(acc.y, off, 64);
        acc.z += __shfl_xor(acc.z, off, 64);
        acc.w += __shfl_xor(acc.w, off, 64);
    }
    if (g == 0) {
        float inv = 1.0f / fmaxf((float)cnt, 1.0f);
        ((float4*)&meanout[(long long)n * 32])[q] =
            make_float4(acc.x * inv, acc.y * inv, acc.z * inv, acc.w * inv);
    }
}

__global__ __launch_bounds__(256) void gather_final_kernel(
    const float* __restrict__ t, const int* __restrict__ rowptr,
    const int* __restrict__ counts, const int* __restrict__ perm,
    const float* __restrict__ r, float* __restrict__ out) {
    int lane = threadIdx.x & 63;
    int wid = threadIdx.x >> 6;
    int n = blockIdx.x * 4 + wid;
    if (n >= N_NODES) return;
    int g = lane >> 3;
    int q = lane & 7;
    int start = rowptr[n];
    int cnt = counts[n];
    int end = start + cnt;
    float4 acc = make_float4(0.f, 0.f, 0.f, 0.f);
    for (int i = start + g; i < end; i += 8) {
        int idx = perm[i];
        float4 v = ((const float4*)&t[(long long)idx * 32])[q];
        acc.x += v.x; acc.y += v.y; acc.z += v.z; acc.w += v.w;
    }
#pragma unroll
    for (int off = 8; off < 64; off <<= 1) {
        acc.x += __shfl_xor(acc.x, off, 64);
        acc.y += __shfl_xor(acc.y, off, 64);
        acc.z += __shfl_xor(acc.z, off, 64);
        acc.w += __shfl_xor(acc.w, off, 64);
    }
    if (g == 0) {
        float inv = 1.0f / fmaxf((float)cnt, 1.0f);
        float4 rv = ((const float4*)&r[(long long)n * 32])[q];
        ((float4*)&out[(long long)n * 32])[q] =
            make_float4(acc.x * inv + rv.x, acc.y * inv + rv.y,
                        acc.z * inv + rv.z, acc.w * inv + rv.w);
    }
}

// ---- per-node dense transform: 2 threads/node ---------------------------
// Thread pair (even,odd lane) shares node n. Each computes 32 of 64 h values
// (wave-uniform broadcast weight reads), exchanges halves via shfl_xor(1),
// then computes 16 t-outputs + 16 r-outputs with contiguous b128 reads from
// transposed W2 in LDS.
__global__ __launch_bounds__(256) void node_transform_kernel(
    const float* __restrict__ x, const float* __restrict__ mean1,
    const float* __restrict__ W1l, const float* __restrict__ W1r,
    const float* __restrict__ b1, const float* __restrict__ W2l,
    const float* __restrict__ W2r, const float* __restrict__ b2,
    float* __restrict__ t, float* __restrict__ r)
{
    __shared__ float sW1l[HID_C * IN_C];    // [j][c] row-major
    __shared__ float sW1r[HID_C * IN_C];
    __shared__ float sW2lT[HID_C * OUT_C];  // [j][k] (transposed)
    __shared__ float sW2rT[HID_C * OUT_C];
    __shared__ float sb1[HID_C];
    __shared__ float sb2[OUT_C];

    for (int i = threadIdx.x; i < HID_C * IN_C; i += 256) {
        sW1l[i] = W1l[i];
        sW1r[i] = W1r[i];
    }
    for (int i = threadIdx.x; i < OUT_C * HID_C; i += 256) {
        int k = i >> 6;        // source row in [32][64]
        int j = i & 63;        // source col
        sW2lT[j * OUT_C + k] = W2l[i];
        sW2rT[j * OUT_C + k] = W2r[i];
    }
    if (threadIdx.x < HID_C) sb1[threadIdx.x] = b1[threadIdx.x];
    if (threadIdx.x < OUT_C) sb2[threadIdx.x] = b2[threadIdx.x];
    __syncthreads();

    int n = blockIdx.x * 128 + (threadIdx.x >> 1);
    int sub = threadIdx.x & 1;
    bool valid = n < N_NODES;

    float4 xq[8], mq[8];
    if (valid) {
        const float4* xp = (const float4*)&x[(long long)n * IN_C];
        const float4* ap = (const float4*)&mean1[(long long)n * IN_C];
#pragma unroll
        for (int c4 = 0; c4 < 8; ++c4) { xq[c4] = xp[c4]; mq[c4] = ap[c4]; }
    } else {
#pragma unroll
        for (int c4 = 0; c4 < 8; ++c4) {
            xq[c4] = make_float4(0.f, 0.f, 0.f, 0.f);
            mq[c4] = make_float4(0.f, 0.f, 0.f, 0.f);
        }
    }

    // layer 1: my half of h
    int jbase = sub * 32;
    float hmine[32];
#pragma unroll
    for (int jj = 0; jj < 32; ++jj) {
        int j = jbase + jj;
        const float4* wl = (const float4*)&sW1l[j * IN_C];
        const float4* wr = (const float4*)&sW1r[j * IN_C];
        float a0 = sb1[j], a1 = 0.f, a2 = 0.f, a3 = 0.f;
#pragma unroll
        for (int c4 = 0; c4 < 8; ++c4) {
            float4 l = wl[c4];
            float4 rr = wr[c4];
            a0 += mq[c4].x * l.x + xq[c4].x * rr.x;
            a1 += mq[c4].y * l.y + xq[c4].y * rr.y;
            a2 += mq[c4].z * l.z + xq[c4].z * rr.z;
            a3 += mq[c4].w * l.w + xq[c4].w * rr.w;
        }
        hmine[jj] = fmaxf((a0 + a1) + (a2 + a3), 0.0f);
    }

    // exchange halves with pair lane
    float hlow[32], hhigh[32];
#pragma unroll
    for (int i = 0; i < 32; ++i) {
        float o = __shfl_xor(hmine[i], 1, 64);
        hlow[i]  = sub ? o : hmine[i];
        hhigh[i] = sub ? hmine[i] : o;
    }

    // layer 2: 16 t + 16 r outputs per thread, contiguous b128 weight reads
    int k0 = sub * 16;
    float tacc[16], racc[16];
#pragma unroll
    for (int i = 0; i < 16; ++i) { tacc[i] = 0.f; racc[i] = sb2[k0 + i]; }

#pragma unroll
    for (int j = 0; j < HID_C; ++j) {
        float hj = (j < 32) ? hlow[j] : hhigh[j - 32];
        const float4* wl = (const float4*)&sW2lT[j * OUT_C + k0];
        const float4* wr = (const float4*)&sW2rT[j * OUT_C + k0];
#pragma unroll
        for (int q = 0; q < 4; ++q) {
            float4 l = wl[q];
            float4 rr = wr[q];
            tacc[q * 4 + 0] += hj * l.x;
            tacc[q * 4 + 1] += hj * l.y;
            tacc[q * 4 + 2] += hj * l.z;
            tacc[q * 4 + 3] += hj * l.w;
            racc[q * 4 + 0] += hj * rr.x;
            racc[q * 4 + 1] += hj * rr.y;
            racc[q * 4 + 2] += hj * rr.z;
            racc[q * 4 + 3] += hj * rr.w;
        }
    }

    if (valid) {
        float4* tp = (float4*)&t[(long long)n * OUT_C + k0];
        float4* rp = (float4*)&r[(long long)n * OUT_C + k0];
#pragma unroll
        for (int q = 0; q < 4; ++q) {
            tp[q] = make_float4(tacc[q * 4 + 0], tacc[q * 4 + 1],
                                tacc[q * 4 + 2], tacc[q * 4 + 3]);
            rp[q] = make_float4(racc[q * 4 + 0], racc[q * 4 + 1],
                                racc[q * 4 + 2], racc[q * 4 + 3]);
        }
    }
}

// ---- launch -------------------------------------------------------------

extern "C" void kernel_launch(void* const* d_in, const int* in_sizes, int n_in,
                              void* d_out, int out_size, void* d_ws, size_t ws_size,
                              hipStream_t stream) {
    const float* x   = (const float*)d_in[0];
    const float* W1l = (const float*)d_in[1];
    const float* W1r = (const float*)d_in[2];
    const float* b1  = (const float*)d_in[3];
    const float* W2l = (const float*)d_in[4];
    const float* W2r = (const float*)d_in[5];
    const float* b2  = (const float*)d_in[6];
    const int*   ei  = (const int*)d_in[7];   // [2, N_EDGES]
    const int* src = ei;
    const int* dst = ei + N_EDGES;

    char* ws = (char*)d_ws;
    int*   counts    = (int*)ws;                ws += (size_t)N_NODES * 4;
    int*   rowptr    = (int*)ws;                ws += (size_t)N_NODES * 4;
    int*   chunkSums = (int*)ws;                ws += 64 * 4;
    int*   chunkOff  = (int*)ws;                ws += 64 * 4;
    int*   gh        = (int*)ws;                ws += (size_t)NB * NBLK * 4;
    int*   perm      = (int*)ws;                ws += (size_t)N_EDGES * 4;
    uint2* tmp       = (uint2*)ws;              ws += (size_t)N_EDGES * 8;
    // mean1 aliases tmp: tmp is dead after node_place_kernel; mean1 written after.
    float* mean1     = (float*)tmp;
    float* t         = (float*)ws;              ws += (size_t)N_NODES * OUT_C * 4;
    float* r         = (float*)ws;              ws += (size_t)N_NODES * OUT_C * 4;

    hipMemsetAsync(counts, 0, (size_t)N_NODES * 4, stream);

    dim3 blk(256);
    int ggrid = (N_NODES + 3) / 4;
    int tgrid = (N_NODES + 127) / 128;   // 2 threads/node

    bucket_hist_kernel<<<NBLK, blk, 0, stream>>>(dst, counts, gh);
    chunk_sum_kernel<<<NCHUNKS, blk, 0, stream>>>(counts, chunkSums);
    chunk_scan_kernel<<<1, 1, 0, stream>>>(chunkSums, chunkOff);
    scan_write_kernel<<<NCHUNKS, blk, 0, stream>>>(counts, chunkOff, rowptr);
    bucket_scan_kernel<<<NB, blk, 0, stream>>>(rowptr, gh);
    bucket_place_kernel<<<NBLK, blk, 0, stream>>>(src, dst, gh, tmp);
    node_place_kernel<<<NB, dim3(512), 0, stream>>>(tmp, rowptr, perm);

    gather_mean_kernel<<<ggrid, blk, 0, stream>>>(x, rowptr, counts, perm, mean1);
    node_transform_kernel<<<tgrid, blk, 0, stream>>>(x, mean1, W1l, W1r, b1,
                                                     W2l, W2r, b2, t, r);
    gather_final_kernel<<<ggrid, blk, 0, stream>>>(t, rowptr, counts, perm, r,
                                                   (float*)d_out);
}

// Round 6
// 269.052 us; speedup vs baseline: 1.9168x; 1.0629x over previous
//
#include <hip/hip_runtime.h>

#define N_NODES 100000
#define N_EDGES 1600000
#define IN_C 32
#define HID_C 64
#define OUT_C 32

#define SCAN_CHUNK 4096
#define NCHUNKS ((N_NODES + SCAN_CHUNK - 1) / SCAN_CHUNK)   // 25

#define EPB 1024                                 // edges per hist/place block
#define NBLK ((N_EDGES + EPB - 1) / EPB)         // 1563
#define BSH 9                                    // 512 nodes per bucket
#define BKN (1 << BSH)
#define NB ((N_NODES + BKN - 1) / BKN)           // 196

// ---- pass A: per-block bucket histogram + global per-node counts --------
__global__ __launch_bounds__(256) void bucket_hist_kernel(
    const int* __restrict__ dst, int* __restrict__ counts, int* __restrict__ gh) {
    __shared__ int lh[NB];
    for (int i = threadIdx.x; i < NB; i += 256) lh[i] = 0;
    __syncthreads();
    int base = blockIdx.x * EPB;
#pragma unroll
    for (int j = 0; j < EPB / 256; ++j) {
        int e = base + j * 256 + threadIdx.x;
        if (e < N_EDGES) {
            int d = dst[e];
            atomicAdd(&lh[d >> BSH], 1);
            atomicAdd(&counts[d], 1);
        }
    }
    __syncthreads();
    for (int i = threadIdx.x; i < NB; i += 256)
        gh[i * NBLK + blockIdx.x] = lh[i];
}

// ---- node-count scan -> rowptr ------------------------------------------
__global__ __launch_bounds__(256) void chunk_sum_kernel(
    const int* __restrict__ counts, int* __restrict__ chunkSums) {
    __shared__ int sd[256];
    int base = blockIdx.x * SCAN_CHUNK + threadIdx.x * 16;
    int s = 0;
#pragma unroll
    for (int i = 0; i < 16; ++i) {
        int n = base + i;
        if (n < N_NODES) s += counts[n];
    }
    sd[threadIdx.x] = s;
    __syncthreads();
    for (int o = 128; o > 0; o >>= 1) {
        if (threadIdx.x < o) sd[threadIdx.x] += sd[threadIdx.x + o];
        __syncthreads();
    }
    if (threadIdx.x == 0) chunkSums[blockIdx.x] = sd[0];
}

__global__ void chunk_scan_kernel(const int* __restrict__ chunkSums,
                                  int* __restrict__ chunkOff) {
    int acc = 0;
    for (int i = 0; i < NCHUNKS; ++i) { chunkOff[i] = acc; acc += chunkSums[i]; }
}

__global__ __launch_bounds__(256) void scan_write_kernel(
    const int* __restrict__ counts, const int* __restrict__ chunkOff,
    int* __restrict__ rowptr) {
    __shared__ int sincl[256];
    int tid = threadIdx.x;
    int base = blockIdx.x * SCAN_CHUNK + tid * 16;
    int local[16];
    int s = 0;
#pragma unroll
    for (int i = 0; i < 16; ++i) {
        int n = base + i;
        int c = (n < N_NODES) ? counts[n] : 0;
        local[i] = s;
        s += c;
    }
    sincl[tid] = s;
    __syncthreads();
    for (int o = 1; o < 256; o <<= 1) {
        int v = (tid >= o) ? sincl[tid - o] : 0;
        __syncthreads();
        sincl[tid] += v;
        __syncthreads();
    }
    int texcl = sincl[tid] - s + chunkOff[blockIdx.x];
#pragma unroll
    for (int i = 0; i < 16; ++i) {
        int n = base + i;
        if (n < N_NODES) rowptr[n] = texcl + local[i];
    }
}

// ---- pass B: per-bucket exclusive scan of gh across blocks --------------
__global__ __launch_bounds__(256) void bucket_scan_kernel(
    const int* __restrict__ rowptr, int* __restrict__ gh) {
    int b = blockIdx.x;
    int t = threadIdx.x;
    __shared__ int ssum[256];
    int v[7];
    int base = t * 7;
    int s = 0;
#pragma unroll
    for (int j = 0; j < 7; ++j) {
        int idx = base + j;
        int val = (idx < NBLK) ? gh[b * NBLK + idx] : 0;
        v[j] = s;
        s += val;
    }
    ssum[t] = s;
    __syncthreads();
    for (int o = 1; o < 256; o <<= 1) {
        int val = (t >= o) ? ssum[t - o] : 0;
        __syncthreads();
        ssum[t] += val;
        __syncthreads();
    }
    int texcl = ssum[t] - s;
    int boff = rowptr[b << BSH];
#pragma unroll
    for (int j = 0; j < 7; ++j) {
        int idx = base + j;
        if (idx < NBLK) gh[b * NBLK + idx] = boff + texcl + v[j];
    }
}

// ---- pass C: place (src,dst) pairs into bucket-sorted tmp ---------------
__global__ __launch_bounds__(256) void bucket_place_kernel(
    const int* __restrict__ src, const int* __restrict__ dst,
    const int* __restrict__ gh, uint2* __restrict__ tmp) {
    __shared__ int cur[NB];
    for (int i = threadIdx.x; i < NB; i += 256)
        cur[i] = gh[i * NBLK + blockIdx.x];
    __syncthreads();
    int base = blockIdx.x * EPB;
#pragma unroll
    for (int j = 0; j < EPB / 256; ++j) {
        int e = base + j * 256 + threadIdx.x;
        if (e < N_EDGES) {
            int d = dst[e];
            int slot = atomicAdd(&cur[d >> BSH], 1);
            tmp[slot] = make_uint2((unsigned)src[e], (unsigned)d);
        }
    }
}

// ---- pass D: within-bucket per-node placement via LDS cursors -----------
__global__ __launch_bounds__(512) void node_place_kernel(
    const uint2* __restrict__ tmp, const int* __restrict__ rowptr,
    int* __restrict__ perm) {
    __shared__ int pos[BKN];
    int b = blockIdx.x;
    int nbase = b << BSH;
    for (int j = threadIdx.x; j < BKN; j += 512) {
        int n = nbase + j;
        pos[j] = (n < N_NODES) ? rowptr[n] : 0;
    }
    __syncthreads();
    int start = rowptr[nbase];
    int end = (b == NB - 1) ? N_EDGES : rowptr[nbase + BKN];
    for (int i = start + threadIdx.x; i < end; i += 512) {
        uint2 p = tmp[i];
        int slot = atomicAdd(&pos[p.y & (BKN - 1)], 1);
        perm[slot] = (int)p.x;
    }
}

// ---- gathers: one wave per node, 8 edges x float4 in flight -------------
__global__ __launch_bounds__(256) void gather_mean_kernel(
    const float* __restrict__ feat, const int* __restrict__ rowptr,
    const int* __restrict__ counts, const int* __restrict__ perm,
    float* __restrict__ meanout) {
    int lane = threadIdx.x & 63;
    int wid = threadIdx.x >> 6;
    int n = blockIdx.x * 4 + wid;
    if (n >= N_NODES) return;
    int g = lane >> 3;
    int q = lane & 7;
    int start = rowptr[n];
    int cnt = counts[n];
    int end = start + cnt;
    float4 acc = make_float4(0.f, 0.f, 0.f, 0.f);
    for (int i = start + g; i < end; i += 8) {
        int idx = perm[i];
        float4 v = ((const float4*)&feat[(long long)idx * 32])[q];
        acc.x += v.x; acc.y += v.y; acc.z += v.z; acc.w += v.w;
    }
#pragma unroll
    for (int off = 8; off < 64; off <<= 1) {
        acc.x += __shfl_xor(acc.x, off, 64);
        acc.y += __shfl_xor(acc.y, off, 64);
        acc.z += __shfl_xor(acc.z, off, 64);
        acc.w += __shfl_xor(acc.w, off, 64);
    }
    if (g == 0) {
        float inv = 1.0f / fmaxf((float)cnt, 1.0f);
        ((float4*)&meanout[(long long)n * 32])[q] =
            make_float4(acc.x * inv, acc.y * inv, acc.z * inv, acc.w * inv);
    }
}

__global__ __launch_bounds__(256) void gather_final_kernel(
    const float* __restrict__ t, const int* __restrict__ rowptr,
    const int* __restrict__ counts, const int* __restrict__ perm,
    const float* __restrict__ r, float* __restrict__ out) {
    int lane = threadIdx.x & 63;
    int wid = threadIdx.x >> 6;
    int n = blockIdx.x * 4 + wid;
    if (n >= N_NODES) return;
    int g = lane >> 3;
    int q = lane & 7;
    int start = rowptr[n];
    int cnt = counts[n];
    int end = start + cnt;
    float4 acc = make_float4(0.f, 0.f, 0.f, 0.f);
    for (int i = start + g; i < end; i += 8) {
        int idx = perm[i];
        float4 v = ((const float4*)&t[(long long)idx * 32])[q];
        acc.x += v.x; acc.y += v.y; acc.z += v.z; acc.w += v.w;
    }
#pragma unroll
    for (int off = 8; off < 64; off <<= 1) {
        acc.x += __shfl_xor(acc.x, off, 64);
        acc.y += __shfl_xor(acc.y, off, 64);
        acc.z += __shfl_xor(acc.z, off, 64);
        acc.w += __shfl_xor(acc.w, off, 64);
    }
    if (g == 0) {
        float inv = 1.0f / fmaxf((float)cnt, 1.0f);
        float4 rv = ((const float4*)&r[(long long)n * 32])[q];
        ((float4*)&out[(long long)n * 32])[q] =
            make_float4(acc.x * inv + rv.x, acc.y * inv + rv.y,
                        acc.z * inv + rv.z, acc.w * inv + rv.w);
    }
}

// ---- per-node dense transform: 4 threads/node, conflict-free LDS --------
// lane = local_node*4 + sub. Layer 1: sub splits the c-reduction (8 floats
// each); weight reads sW1*[j*32 + sub*8] hit distinct banks per sub and are
// 16-lane broadcast otherwise -> conflict-free b128. h_j completed in all 4
// lanes via 2x shfl_xor butterfly. Layer 2: sub owns k = sub*8..+7; W2 is
// staged transposed with row stride 36 ((4j+k)%32 covers all 32 banks across
// subs -> conflict-free b128, 16B-aligned). No h materialization.
#define W2S 36
__global__ __launch_bounds__(256) void node_transform_kernel(
    const float* __restrict__ x, const float* __restrict__ mean1,
    const float* __restrict__ W1l, const float* __restrict__ W1r,
    const float* __restrict__ b1, const float* __restrict__ W2l,
    const float* __restrict__ W2r, const float* __restrict__ b2,
    float* __restrict__ t, float* __restrict__ r)
{
    __shared__ float sW1l[HID_C * IN_C];     // [j][c]
    __shared__ float sW1r[HID_C * IN_C];
    __shared__ float sW2lT[HID_C * W2S];     // [j][k], stride 36
    __shared__ float sW2rT[HID_C * W2S];
    __shared__ float sb1[HID_C];
    __shared__ float sb2[OUT_C];

    for (int i = threadIdx.x; i < HID_C * IN_C; i += 256) {
        sW1l[i] = W1l[i];
        sW1r[i] = W1r[i];
    }
    for (int i = threadIdx.x; i < OUT_C * HID_C; i += 256) {
        int k = i >> 6;        // source row of W2 [32][64]
        int j = i & 63;        // source col
        sW2lT[j * W2S + k] = W2l[i];
        sW2rT[j * W2S + k] = W2r[i];
    }
    if (threadIdx.x < HID_C) sb1[threadIdx.x] = b1[threadIdx.x];
    if (threadIdx.x < OUT_C) sb2[threadIdx.x] = b2[threadIdx.x];
    __syncthreads();

    int sub = threadIdx.x & 3;
    int n = blockIdx.x * 64 + (threadIdx.x >> 2);
    bool valid = n < N_NODES;
    int c0 = sub * 8;          // this lane's c-chunk (layer 1)
    int k0 = sub * 8;          // this lane's k-chunk (layer 2)

    float4 xq0, xq1, mq0, mq1;
    if (valid) {
        const float4* xp = (const float4*)&x[(long long)n * IN_C + c0];
        const float4* mp = (const float4*)&mean1[(long long)n * IN_C + c0];
        xq0 = xp[0]; xq1 = xp[1];
        mq0 = mp[0]; mq1 = mp[1];
    } else {
        xq0 = xq1 = mq0 = mq1 = make_float4(0.f, 0.f, 0.f, 0.f);
    }

    float tacc[8], racc[8];
#pragma unroll
    for (int i = 0; i < 8; ++i) { tacc[i] = 0.f; racc[i] = sb2[k0 + i]; }

#pragma unroll 8
    for (int j = 0; j < HID_C; ++j) {
        const float4* wl = (const float4*)&sW1l[j * IN_C + c0];
        const float4* wr = (const float4*)&sW1r[j * IN_C + c0];
        float4 l0 = wl[0], l1 = wl[1];
        float4 r0 = wr[0], r1 = wr[1];
        float pl = mq0.x * l0.x + mq0.y * l0.y + mq0.z * l0.z + mq0.w * l0.w
                 + mq1.x * l1.x + mq1.y * l1.y + mq1.z * l1.z + mq1.w * l1.w;
        float pr = xq0.x * r0.x + xq0.y * r0.y + xq0.z * r0.z + xq0.w * r0.w
                 + xq1.x * r1.x + xq1.y * r1.y + xq1.z * r1.z + xq1.w * r1.w;
        float p = pl + pr;
        p += __shfl_xor(p, 1, 64);
        p += __shfl_xor(p, 2, 64);
        float hj = fmaxf(p + sb1[j], 0.0f);

        const float4* w2l = (const float4*)&sW2lT[j * W2S + k0];
        const float4* w2r = (const float4*)&sW2rT[j * W2S + k0];
        float4 a0 = w2l[0], a1 = w2l[1];
        float4 c0v = w2r[0], c1v = w2r[1];
        tacc[0] += hj * a0.x; tacc[1] += hj * a0.y;
        tacc[2] += hj * a0.z; tacc[3] += hj * a0.w;
        tacc[4] += hj * a1.x; tacc[5] += hj * a1.y;
        tacc[6] += hj * a1.z; tacc[7] += hj * a1.w;
        racc[0] += hj * c0v.x; racc[1] += hj * c0v.y;
        racc[2] += hj * c0v.z; racc[3] += hj * c0v.w;
        racc[4] += hj * c1v.x; racc[5] += hj * c1v.y;
        racc[6] += hj * c1v.z; racc[7] += hj * c1v.w;
    }

    if (valid) {
        float4* tp = (float4*)&t[(long long)n * OUT_C + k0];
        float4* rp = (float4*)&r[(long long)n * OUT_C + k0];
        tp[0] = make_float4(tacc[0], tacc[1], tacc[2], tacc[3]);
        tp[1] = make_float4(tacc[4], tacc[5], tacc[6], tacc[7]);
        rp[0] = make_float4(racc[0], racc[1], racc[2], racc[3]);
        rp[1] = make_float4(racc[4], racc[5], racc[6], racc[7]);
    }
}

// ---- launch -------------------------------------------------------------

extern "C" void kernel_launch(void* const* d_in, const int* in_sizes, int n_in,
                              void* d_out, int out_size, void* d_ws, size_t ws_size,
                              hipStream_t stream) {
    const float* x   = (const float*)d_in[0];
    const float* W1l = (const float*)d_in[1];
    const float* W1r = (const float*)d_in[2];
    const float* b1  = (const float*)d_in[3];
    const float* W2l = (const float*)d_in[4];
    const float* W2r = (const float*)d_in[5];
    const float* b2  = (const float*)d_in[6];
    const int*   ei  = (const int*)d_in[7];   // [2, N_EDGES]
    const int* src = ei;
    const int* dst = ei + N_EDGES;

    char* ws = (char*)d_ws;
    int*   counts    = (int*)ws;                ws += (size_t)N_NODES * 4;
    int*   rowptr    = (int*)ws;                ws += (size_t)N_NODES * 4;
    int*   chunkSums = (int*)ws;                ws += 64 * 4;
    int*   chunkOff  = (int*)ws;                ws += 64 * 4;
    int*   gh        = (int*)ws;                ws += (size_t)NB * NBLK * 4;
    int*   perm      = (int*)ws;                ws += (size_t)N_EDGES * 4;
    uint2* tmp       = (uint2*)ws;              ws += (size_t)N_EDGES * 8;
    // mean1 aliases tmp: tmp is dead after node_place_kernel; mean1 written after.
    float* mean1     = (float*)tmp;
    float* t         = (float*)ws;              ws += (size_t)N_NODES * OUT_C * 4;
    float* r         = (float*)ws;              ws += (size_t)N_NODES * OUT_C * 4;

    hipMemsetAsync(counts, 0, (size_t)N_NODES * 4, stream);

    dim3 blk(256);
    int ggrid = (N_NODES + 3) / 4;
    int tgrid = (N_NODES + 63) / 64;   // 4 threads/node, 64 nodes/block

    bucket_hist_kernel<<<NBLK, blk, 0, stream>>>(dst, counts, gh);
    chunk_sum_kernel<<<NCHUNKS, blk, 0, stream>>>(counts, chunkSums);
    chunk_scan_kernel<<<1, 1, 0, stream>>>(chunkSums, chunkOff);
    scan_write_kernel<<<NCHUNKS, blk, 0, stream>>>(counts, chunkOff, rowptr);
    bucket_scan_kernel<<<NB, blk, 0, stream>>>(rowptr, gh);
    bucket_place_kernel<<<NBLK, blk, 0, stream>>>(src, dst, gh, tmp);
    node_place_kernel<<<NB, dim3(512), 0, stream>>>(tmp, rowptr, perm);

    gather_mean_kernel<<<ggrid, blk, 0, stream>>>(x, rowptr, counts, perm, mean1);
    node_transform_kernel<<<tgrid, blk, 0, stream>>>(x, mean1, W1l, W1r, b1,
                                                     W2l, W2r, b2, t, r);
    gather_final_kernel<<<ggrid, blk, 0, stream>>>(t, rowptr, counts, perm, r,
                                                   (float*)d_out);
}